// Round 4
// baseline (85.357 us; speedup 1.0000x reference)
//
#include <hip/hip_runtime.h>
#include <hip/hip_bf16.h>

// Decompose: algebraically a single 5x5 conv with scalar taps
//   a_k = wS_k . wE_k  (k = i*5+j), bias = sum_k (wS_k . bE_k + bS_k)
//   out = clip( (sum_k a_k * xp[h+i, w+j] + bias) / 25, 0, 1 )
// over xp = reflect-pad(clip(x,0,1), 2). Shapes: x (4,3,1024,1024) fp32.
//
// R4: single fused kernel. Each wave redundantly computes the 26 constants
// (75 coalesced loads from the 25KB weight table + __shfl_xor butterfly
// reduce), then readfirstlane -> SGPRs so the conv main loop keeps scalar
// weight operands. Removes the serialized 1-block prep kernel + launch.

#define HH 1024
#define WW 1024
#define NIMG 12
#define TBH 8              // output rows per thread/block-row
#define ROWS (TBH + 4)     // 12 input rows touched

typedef float f32x4 __attribute__((ext_vector_type(4)));

__device__ __forceinline__ float clip01(float v) {
    return fminf(fmaxf(v, 0.f), 1.f);
}

__device__ __forceinline__ float sgpr_bcast(float v) {
    return __int_as_float(__builtin_amdgcn_readfirstlane(__float_as_int(v)));
}

__global__ __launch_bounds__(256, 6) void conv5_kernel(const float* __restrict__ x,
                                                       const float* __restrict__ wE,
                                                       const float* __restrict__ bE,
                                                       const float* __restrict__ wS,
                                                       const float* __restrict__ bS,
                                                       float* __restrict__ out) {
    // ---- Per-wave constant computation (DIM == 64 == wave size) ----
    int lane = threadIdx.x & 63;
    float apart[25];
    float cpart = 0.f;
    #pragma unroll
    for (int k = 0; k < 25; ++k) {
        float s = wS[k * 64 + lane];
        apart[k] = s * wE[k * 64 + lane];
        cpart = fmaf(s, bE[k * 64 + lane], cpart);
    }
    if (lane < 25) cpart += bS[lane];
    #pragma unroll
    for (int off = 32; off; off >>= 1) {
        cpart += __shfl_xor(cpart, off);
        #pragma unroll
        for (int k = 0; k < 25; ++k) apart[k] += __shfl_xor(apart[k], off);
    }
    float wv[25];
    #pragma unroll
    for (int k = 0; k < 25; ++k) wv[k] = sgpr_bcast(apart[k] * (1.f / 25.f));
    float bias = sgpr_bcast(cpart * (1.f / 25.f));

    // ---- Tile mapping: XCD-aware bijective swizzle (1536 % 8 == 0) ----
    int nwg = gridDim.x;
    int cpx = nwg >> 3;
    int l = (blockIdx.x & 7) * cpx + (blockIdx.x >> 3);
    int img = l >> 7;                         // 128 row-blocks per image
    int rb = l & 127;
    int row0 = rb * TBH;

    const float* src = x + (size_t)img * (HH * WW);
    int tid = threadIdx.x;
    int cbase = tid * 4;                      // output col base

    // Column window: need source cols cbase-2 .. cbase+5 (reflect at edges).
    bool lt = (cbase == 0);
    bool rt = (cbase == 1020);
    int qa = lt ? 0 : cbase - 2;
    int qb = rt ? 1020 : cbase + 2;

    float acc[TBH][4];
    #pragma unroll
    for (int r = 0; r < TBH; ++r)
        #pragma unroll
        for (int c = 0; c < 4; ++c) acc[r][c] = 0.f;

    #pragma unroll
    for (int ir = 0; ir < ROWS; ++ir) {
        int prow = row0 - 2 + ir;
        int sr = prow < 0 ? -prow : (prow >= HH ? 2 * HH - 2 - prow : prow);
        const float* rp = src + (size_t)sr * WW;
        f32x4 A = *(const f32x4*)(rp + qa);
        f32x4 B = *(const f32x4*)(rp + qb);

        float r8[8];
        if (lt) {
            r8[0]=A.z; r8[1]=A.y; r8[2]=A.x; r8[3]=A.y;
            r8[4]=B.x; r8[5]=B.y; r8[6]=B.z; r8[7]=B.w;
        } else if (rt) {
            r8[0]=A.x; r8[1]=A.y; r8[2]=A.z; r8[3]=A.w;
            r8[4]=B.z; r8[5]=B.w; r8[6]=B.z; r8[7]=B.y;
        } else {
            r8[0]=A.x; r8[1]=A.y; r8[2]=A.z; r8[3]=A.w;
            r8[4]=B.x; r8[5]=B.y; r8[6]=B.z; r8[7]=B.w;
        }
        #pragma unroll
        for (int j = 0; j < 8; ++j) r8[j] = clip01(r8[j]);

        #pragma unroll
        for (int dr = 0; dr < 5; ++dr) {
            int orow = ir - dr;
            if (orow < 0 || orow >= TBH) continue;
            #pragma unroll
            for (int j = 0; j < 5; ++j) {
                float wj = wv[dr * 5 + j];
                #pragma unroll
                for (int c = 0; c < 4; ++c)
                    acc[orow][c] = fmaf(wj, r8[c + j], acc[orow][c]);
            }
        }
    }

    // Epilogue: bias, clip, nontemporal coalesced 16B stores.
    float* op = out + (size_t)img * (HH * WW) + (size_t)row0 * WW + cbase;
    #pragma unroll
    for (int orow = 0; orow < TBH; ++orow) {
        f32x4 o;
        o.x = clip01(acc[orow][0] + bias);
        o.y = clip01(acc[orow][1] + bias);
        o.z = clip01(acc[orow][2] + bias);
        o.w = clip01(acc[orow][3] + bias);
        __builtin_nontemporal_store(o, (f32x4*)(op + (size_t)orow * WW));
    }
}

extern "C" void kernel_launch(void* const* d_in, const int* in_sizes, int n_in,
                              void* d_out, int out_size, void* d_ws, size_t ws_size,
                              hipStream_t stream) {
    const float* x  = (const float*)d_in[0];
    const float* wE = (const float*)d_in[1];
    const float* bE = (const float*)d_in[2];
    const float* wS = (const float*)d_in[3];
    const float* bS = (const float*)d_in[4];
    float* out = (float*)d_out;

    int nblocks = NIMG * (HH / TBH);   // 12 * 128 = 1536
    conv5_kernel<<<nblocks, 256, 0, stream>>>(x, wE, bE, wS, bS, out);
}

// Round 5
// 30.551 us; speedup vs baseline: 2.7939x; 2.7939x over previous
//
#include <hip/hip_runtime.h>
#include <hip/hip_bf16.h>

// Decompose: algebraically a single 5x5 conv with scalar taps
//   a_k = wS_k . wE_k  (k = i*5+j), bias = sum_k (wS_k . bE_k + bS_k)
//   out = clip( (sum_k a_k * xp[h+i, w+j] + bias) / 25, 0, 1 )
// over xp = reflect-pad(clip(x,0,1), 2). Shapes: x (4,3,1024,1024) fp32.
//
// R5: fused single kernel, register-pressure-safe prep. Each wave computes
// the 26 constants one tap at a time (2 coalesced loads -> mul -> 6x shfl_xor
// -> readfirstlane to SGPR), so only ~3 extra VGPRs are ever live. No
// launch_bounds min-waves cap (R4's cap at 40 VGPR caused 300MB of spill
// traffic: FETCH 143MB / WRITE 214MB).

#define HH 1024
#define WW 1024
#define NIMG 12
#define TBH 8              // output rows per thread/block-row
#define ROWS (TBH + 4)     // 12 input rows touched

typedef float f32x4 __attribute__((ext_vector_type(4)));

__device__ __forceinline__ float clip01(float v) {
    return fminf(fmaxf(v, 0.f), 1.f);
}

__device__ __forceinline__ float sgpr_bcast(float v) {
    return __int_as_float(__builtin_amdgcn_readfirstlane(__float_as_int(v)));
}

__global__ __launch_bounds__(256) void conv5_kernel(const float* __restrict__ x,
                                                    const float* __restrict__ wE,
                                                    const float* __restrict__ bE,
                                                    const float* __restrict__ wS,
                                                    const float* __restrict__ bS,
                                                    float* __restrict__ out) {
    // ---- Per-wave constant computation (DIM == 64 == wave size) ----
    // One tap at a time: only ~3 live VGPRs; results go uniform -> SGPRs.
    int lane = threadIdx.x & 63;
    float wv[25];
    float cpart = 0.f;
    #pragma unroll
    for (int k = 0; k < 25; ++k) {
        float s = wS[k * 64 + lane];
        float p = s * wE[k * 64 + lane];
        cpart = fmaf(s, bE[k * 64 + lane], cpart);
        #pragma unroll
        for (int off = 32; off; off >>= 1) p += __shfl_xor(p, off);
        wv[k] = sgpr_bcast(p * (1.f / 25.f));
    }
    if (lane < 25) cpart += bS[lane];
    #pragma unroll
    for (int off = 32; off; off >>= 1) cpart += __shfl_xor(cpart, off);
    float bias = sgpr_bcast(cpart * (1.f / 25.f));

    // ---- Tile mapping: XCD-aware bijective swizzle (1536 % 8 == 0) ----
    int nwg = gridDim.x;
    int cpx = nwg >> 3;
    int l = (blockIdx.x & 7) * cpx + (blockIdx.x >> 3);
    int img = l >> 7;                         // 128 row-blocks per image
    int rb = l & 127;
    int row0 = rb * TBH;

    const float* src = x + (size_t)img * (HH * WW);
    int tid = threadIdx.x;
    int cbase = tid * 4;                      // output col base

    // Column window: need source cols cbase-2 .. cbase+5 (reflect at edges).
    bool lt = (cbase == 0);
    bool rt = (cbase == 1020);
    int qa = lt ? 0 : cbase - 2;
    int qb = rt ? 1020 : cbase + 2;

    float acc[TBH][4];
    #pragma unroll
    for (int r = 0; r < TBH; ++r)
        #pragma unroll
        for (int c = 0; c < 4; ++c) acc[r][c] = 0.f;

    #pragma unroll
    for (int ir = 0; ir < ROWS; ++ir) {
        int prow = row0 - 2 + ir;
        int sr = prow < 0 ? -prow : (prow >= HH ? 2 * HH - 2 - prow : prow);
        const float* rp = src + (size_t)sr * WW;
        f32x4 A = *(const f32x4*)(rp + qa);
        f32x4 B = *(const f32x4*)(rp + qb);

        float r8[8];
        if (lt) {
            r8[0]=A.z; r8[1]=A.y; r8[2]=A.x; r8[3]=A.y;
            r8[4]=B.x; r8[5]=B.y; r8[6]=B.z; r8[7]=B.w;
        } else if (rt) {
            r8[0]=A.x; r8[1]=A.y; r8[2]=A.z; r8[3]=A.w;
            r8[4]=B.z; r8[5]=B.w; r8[6]=B.z; r8[7]=B.y;
        } else {
            r8[0]=A.x; r8[1]=A.y; r8[2]=A.z; r8[3]=A.w;
            r8[4]=B.x; r8[5]=B.y; r8[6]=B.z; r8[7]=B.w;
        }
        #pragma unroll
        for (int j = 0; j < 8; ++j) r8[j] = clip01(r8[j]);

        #pragma unroll
        for (int dr = 0; dr < 5; ++dr) {
            int orow = ir - dr;
            if (orow < 0 || orow >= TBH) continue;
            #pragma unroll
            for (int j = 0; j < 5; ++j) {
                float wj = wv[dr * 5 + j];
                #pragma unroll
                for (int c = 0; c < 4; ++c)
                    acc[orow][c] = fmaf(wj, r8[c + j], acc[orow][c]);
            }
        }
    }

    // Epilogue: bias, clip, nontemporal coalesced 16B stores.
    float* op = out + (size_t)img * (HH * WW) + (size_t)row0 * WW + cbase;
    #pragma unroll
    for (int orow = 0; orow < TBH; ++orow) {
        f32x4 o;
        o.x = clip01(acc[orow][0] + bias);
        o.y = clip01(acc[orow][1] + bias);
        o.z = clip01(acc[orow][2] + bias);
        o.w = clip01(acc[orow][3] + bias);
        __builtin_nontemporal_store(o, (f32x4*)(op + (size_t)orow * WW));
    }
}

extern "C" void kernel_launch(void* const* d_in, const int* in_sizes, int n_in,
                              void* d_out, int out_size, void* d_ws, size_t ws_size,
                              hipStream_t stream) {
    const float* x  = (const float*)d_in[0];
    const float* wE = (const float*)d_in[1];
    const float* bE = (const float*)d_in[2];
    const float* wS = (const float*)d_in[3];
    const float* bS = (const float*)d_in[4];
    float* out = (float*)d_out;

    int nblocks = NIMG * (HH / TBH);   // 12 * 128 = 1536
    conv5_kernel<<<nblocks, 256, 0, stream>>>(x, wE, bE, wS, bS, out);
}